// Round 1
// 471.292 us; speedup vs baseline: 1.3067x; 1.3067x over previous
//
#include <hip/hip_runtime.h>

// Decoder: Bahdanau attention + GRU cell + vocab projection
// VOCAB=32000, EMB=512, H=1024, B=64, S=128
// Inputs fp32, dec_input int32. Output fp32 flat:
//   probs(64x32000) | state(64x1024) | attn(64x128)
// GEMMs via bf16 MFMA (v_mfma_f32_16x16x32_bf16), fp32 accumulate.
// Verified fragment layouts (learn_hip m89/m91/m120):
//   A: lane holds A[m=lane&15][k=(lane>>4)*8 + j], j=0..7 (8 bf16, b128)
//   B: lane holds B[k=(lane>>4)*8 + j][n=lane&15]
//   C/D: row=(lane>>4)*4+reg, col=lane&15
//
// R1: conflict-free staging. Old B staging wrote 4 scalar u16 at stride
// 320B (80 dw = 16 mod 32 -> ~16-way bank conflict); SQ_LDS_BANK_CONFLICT
// was ~60% of score kernel's cycles. New scheme:
//   A: one ds_write_b128/thread into [64][32] bf16 with 16B-chunk XOR swizzle
//      slot' = slot ^ ((r ^ r>>2)&3)  -> writes & b128 frag reads <=2-way.
//   B: stage fp32 [32][NT] raw tile (coalesced float4, group ^= (kr>>3)&3),
//      barrier, then WAVE-LOCAL transpose+convert (8 scalar col reads ->
//      one swizzled b128 write). Same-wave DS ops are in-order -> frag
//      reads need no extra barrier. 2 barriers per k-step total.

#define B_ 64
#define S_ 128
#define H_ 1024
#define EMB_ 512
#define VOCAB_ 32000

typedef __attribute__((ext_vector_type(8))) short short8;
typedef __attribute__((ext_vector_type(4))) float f32x4;

__device__ __forceinline__ unsigned short f2bf_bits(float f) {
    unsigned int u = __float_as_uint(f);
    u += 0x7FFF + ((u >> 16) & 1);  // round-to-nearest-even
    return (unsigned short)(u >> 16);
}
__device__ __forceinline__ float sigmoidf_(float x) { return 1.0f / (1.0f + expf(-x)); }
// 16B-slot swizzle key for bf16 row r: spreads rows r, r+4, r+8, r+12 apart.
__device__ __forceinline__ int sw_(int r) { return (r ^ (r >> 2)) & 3; }

// ---------------------------------------------------------------------------
// Tile GEMM core: C_tile(64 x 64*NF) += A(64xK slice) * W(K x N) over k0..k1.
// A fp32 row-major (lda), W fp32 row-major (ldw). bf16 conversion on the fly.
// Block = 256 threads = 4 waves; wave w covers cols [w*16*NF, w*16*NF+16*NF).
// ---------------------------------------------------------------------------
template <int NF>
__device__ void mfma_gemm_tile(const float* __restrict__ A, int lda,
                               const float* __restrict__ W, int ldw,
                               int m_base, int n_base, int k0, int k1,
                               f32x4 (&acc)[4][NF]) {
    constexpr int NT = 64 * NF;  // tile cols
    __shared__ __attribute__((aligned(16))) float Braw[32 * NT];
    __shared__ __attribute__((aligned(16))) unsigned short A_lds[64 * 32];
    __shared__ __attribute__((aligned(16))) unsigned short B_lds[NT * 32];
    const int tid = threadIdx.x;
    const int w = tid >> 6, lane = tid & 63, quad = lane >> 4, l15 = lane & 15;

    const f32x4 z = {0.0f, 0.0f, 0.0f, 0.0f};
#pragma unroll
    for (int mi = 0; mi < 4; ++mi)
#pragma unroll
        for (int ni = 0; ni < NF; ++ni) acc[mi][ni] = z;

    const int ar = tid >> 2, ac = tid & 3;  // A staging: row, 16B k-chunk
    const int aslot = ac ^ sw_(ar);

    for (int k = k0; k < k1; k += 32) {
        // ---- stage 1a: A 64x32 fp32 -> bf16, one b128 write per thread ----
        {
            const float* src = A + (size_t)(m_base + ar) * lda + k + 8 * ac;
            float4 v0 = *(const float4*)src;
            float4 v1 = *(const float4*)(src + 4);
            short8 s;
            s[0] = (short)f2bf_bits(v0.x);
            s[1] = (short)f2bf_bits(v0.y);
            s[2] = (short)f2bf_bits(v0.z);
            s[3] = (short)f2bf_bits(v0.w);
            s[4] = (short)f2bf_bits(v1.x);
            s[5] = (short)f2bf_bits(v1.y);
            s[6] = (short)f2bf_bits(v1.z);
            s[7] = (short)f2bf_bits(v1.w);
            *(short8*)&A_lds[ar * 32 + aslot * 8] = s;
        }
        // ---- stage 1b: B raw fp32 [32][NT], coalesced, float4-group swizzle
        //      group cs = c4 ^ ((kr>>3)&3) so stage-2 column reads spread ----
#pragma unroll
        for (int it = 0; it < 2 * NF; ++it) {
            int idx = tid + 256 * it;  // 0 .. 8*NT-1 float4 jobs
            int kr = idx / (NT / 4), c4 = idx % (NT / 4);
            int cs = c4 ^ ((kr >> 3) & 3);
            *(float4*)&Braw[kr * NT + 4 * cs] =
                *(const float4*)(W + (size_t)(k + kr) * ldw + n_base + 4 * c4);
        }
        __syncthreads();

        // ---- stage 2 (wave-local): transpose+convert this wave's 16*NF rows.
        //      Same-wave DS in-order => no barrier before frag reads. ----
        short8 bfrag[NF];
#pragma unroll
        for (int i = 0; i < NF; ++i) {
            int s = i * 64 + lane;           // 64*NF jobs: (row, k-slot)
            int n = w * 16 * NF + (s >> 2);  // tile-relative col this wave owns
            int slot = s & 3;                // k-chunk (8 k's)
            short8 sv;
#pragma unroll
            for (int j = 0; j < 8; ++j) {
                float f = Braw[(slot * 8 + j) * NT + 4 * ((n >> 2) ^ slot) + (n & 3)];
                sv[j] = (short)f2bf_bits(f);
            }
            *(short8*)&B_lds[n * 32 + (slot ^ sw_(n)) * 8] = sv;
        }
#pragma unroll
        for (int ni = 0; ni < NF; ++ni) {
            int n = w * 16 * NF + 16 * ni + l15;
            bfrag[ni] = *(const short8*)&B_lds[n * 32 + (quad ^ sw_(n)) * 8];
        }
#pragma unroll
        for (int mi = 0; mi < 4; ++mi) {
            int r = 16 * mi + l15;
            short8 afrag = *(const short8*)&A_lds[r * 32 + (quad ^ sw_(r)) * 8];
#pragma unroll
            for (int ni = 0; ni < NF; ++ni)
                acc[mi][ni] = __builtin_amdgcn_mfma_f32_16x16x32_bf16(
                    afrag, bfrag[ni], acc[mi][ni], 0, 0, 0);
        }
        __syncthreads();
    }
}

// ---------------------------------------------------------------------------
// Fused bias pre-init for all atomic-accumulate targets (was 4 launches).
// Segments: hproj[B*H] | hm[B*3H] | xm[B*3H] | score[B*S]
// ---------------------------------------------------------------------------
__global__ void init_bias4_kernel(float* __restrict__ hproj, const float* __restrict__ W2_b,
                                  float* __restrict__ hm, float* __restrict__ xm,
                                  const float* __restrict__ gru_b,
                                  float* __restrict__ score, const float* __restrict__ V_b) {
    int i = blockIdx.x * 256 + threadIdx.x;
    const int E0 = B_ * H_;
    const int E1 = E0 + B_ * 3 * H_;
    const int E2 = E1 + B_ * 3 * H_;
    const int E3 = E2 + B_ * S_;
    if (i < E0) {
        hproj[i] = W2_b[i & (H_ - 1)];
    } else if (i < E1) {
        int j = i - E0;
        hm[j] = gru_b[3 * H_ + j % (3 * H_)];
    } else if (i < E2) {
        int j = i - E1;
        xm[j] = gru_b[j % (3 * H_)];
    } else if (i < E3) {
        score[i - E2] = V_b[0];
    }
}

// ---------------------------------------------------------------------------
// Skinny GEMM (M=64), K-split across blockIdx.y, atomicAdd into pre-inited C.
// ---------------------------------------------------------------------------
template <int NF>
__global__ __launch_bounds__(256) void gemm_mfma_atomic_kernel(
    const float* __restrict__ A, int lda, const float* __restrict__ W, int ldw,
    float* __restrict__ C, int kslice) {
    f32x4 acc[4][NF];
    const int n_base = blockIdx.x * 64 * NF;
    const int k0 = blockIdx.y * kslice;
    mfma_gemm_tile<NF>(A, lda, W, ldw, 0, n_base, k0, k0 + kslice, acc);
    const int tid = threadIdx.x, w = tid >> 6, lane = tid & 63;
    const int quad = lane >> 4, l15 = lane & 15;
#pragma unroll
    for (int mi = 0; mi < 4; ++mi)
#pragma unroll
        for (int ni = 0; ni < NF; ++ni) {
            int col = n_base + w * 16 * NF + 16 * ni + l15;
#pragma unroll
            for (int r = 0; r < 4; ++r) {
                int row = 16 * mi + quad * 4 + r;
                atomicAdd(&C[(size_t)row * ldw + col], acc[mi][ni][r]);
            }
        }
}

// ---------------------------------------------------------------------------
// score: feat = enc @ W1 (this block: 64 (b,s)-rows x 256 feat-cols), then
// partial score = sum_k tanh(feat + W1b[k] + hproj[b][k]) * Vk[k], reduced
// across the 16 lanes sharing a quad, atomicAdd into V_b-pre-inited score.
// ---------------------------------------------------------------------------
__global__ __launch_bounds__(256) void score_mfma_kernel(
    const float* __restrict__ enc, const float* __restrict__ W1,
    const float* __restrict__ W1b, const float* __restrict__ Vk,
    const float* __restrict__ hproj, float* __restrict__ score) {
    f32x4 acc[4][4];
    const int n_base = blockIdx.x * 256;
    const int m_base = blockIdx.y * 64;
    const int b = m_base >> 7, s_base = m_base & 127;
    mfma_gemm_tile<4>(enc, H_, W1, H_, m_base, n_base, 0, H_, acc);

    const int tid = threadIdx.x, w = tid >> 6, lane = tid & 63;
    const int quad = lane >> 4, l15 = lane & 15;

    float rowpart[4][4];
#pragma unroll
    for (int mi = 0; mi < 4; ++mi)
#pragma unroll
        for (int r = 0; r < 4; ++r) rowpart[mi][r] = 0.0f;

#pragma unroll
    for (int ni = 0; ni < 4; ++ni) {
        int kcol = n_base + w * 64 + 16 * ni + l15;
        float add = W1b[kcol] + hproj[(size_t)b * H_ + kcol];
        float vv = Vk[kcol];
#pragma unroll
        for (int mi = 0; mi < 4; ++mi)
#pragma unroll
            for (int r = 0; r < 4; ++r)
                rowpart[mi][r] += tanhf(acc[mi][ni][r] + add) * vv;
    }
    // reduce across the 16 lanes with the same quad (xor over bits 0..3)
#pragma unroll
    for (int m = 1; m <= 8; m <<= 1)
#pragma unroll
        for (int mi = 0; mi < 4; ++mi)
#pragma unroll
            for (int r = 0; r < 4; ++r)
                rowpart[mi][r] += __shfl_xor(rowpart[mi][r], m, 64);
    if (l15 == 0) {
#pragma unroll
        for (int mi = 0; mi < 4; ++mi)
#pragma unroll
            for (int r = 0; r < 4; ++r)
                atomicAdd(&score[b * S_ + s_base + 16 * mi + quad * 4 + r],
                          rowpart[mi][r]);
    }
}

// ---------------------------------------------------------------------------
// probs = state @ out_k + out_b (M=64, N=32000, K=1024), direct store.
// ---------------------------------------------------------------------------
__global__ __launch_bounds__(256) void probs_mfma_kernel(
    const float* __restrict__ state, const float* __restrict__ out_k,
    const float* __restrict__ out_b, float* __restrict__ probs) {
    f32x4 acc[4][2];
    const int n_base = blockIdx.x * 128;
    mfma_gemm_tile<2>(state, H_, out_k, VOCAB_, 0, n_base, 0, H_, acc);
    const int tid = threadIdx.x, w = tid >> 6, lane = tid & 63;
    const int quad = lane >> 4, l15 = lane & 15;
#pragma unroll
    for (int mi = 0; mi < 4; ++mi)
#pragma unroll
        for (int ni = 0; ni < 2; ++ni) {
            int col = n_base + w * 32 + 16 * ni + l15;
            float bv = out_b[col];
#pragma unroll
            for (int r = 0; r < 4; ++r) {
                int row = 16 * mi + quad * 4 + r;
                probs[(size_t)row * VOCAB_ + col] = acc[mi][ni][r] + bv;
            }
        }
}

// ---------------------------------------------------------------------------
// softmax over S per batch -> fp32 attn output region
// ---------------------------------------------------------------------------
__global__ void softmax_kernel(const float* __restrict__ score,
                               float* __restrict__ attn_out) {
    const int b = blockIdx.x;
    const int s = threadIdx.x;  // 128 threads
    __shared__ float red[128];
    float v = score[b * S_ + s];
    red[s] = v;
    __syncthreads();
    for (int str = 64; str > 0; str >>= 1) {
        if (s < str) red[s] = fmaxf(red[s], red[s + str]);
        __syncthreads();
    }
    float m = red[0];
    __syncthreads();
    float e = expf(v - m);
    red[s] = e;
    __syncthreads();
    for (int str = 64; str > 0; str >>= 1) {
        if (s < str) red[s] += red[s + str];
        __syncthreads();
    }
    attn_out[b * S_ + s] = e / red[0];
}

// ---------------------------------------------------------------------------
// context[b,h] = sum_s attn[b,s] * enc[b,s,h]
// ---------------------------------------------------------------------------
__global__ void context_kernel(const float* __restrict__ attn,
                               const float* __restrict__ enc,
                               float* __restrict__ ctx) {
    const int b = blockIdx.x >> 2;
    const int h = ((blockIdx.x & 3) << 8) + threadIdx.x;
    __shared__ float aw[S_];
    if (threadIdx.x < S_) aw[threadIdx.x] = attn[b * S_ + threadIdx.x];
    __syncthreads();
    float acc = 0.0f;
    for (int s = 0; s < S_; ++s)
        acc += aw[s] * enc[((size_t)b * S_ + s) * H_ + h];
    ctx[(size_t)b * H_ + h] = acc;
}

// ---------------------------------------------------------------------------
// x[b,:] = concat(context[b,:], emb[dec[b],:])
// ---------------------------------------------------------------------------
__global__ void buildx_kernel(const float* __restrict__ ctx, const float* __restrict__ emb,
                              const int* __restrict__ dec, float* __restrict__ x) {
    const int b = blockIdx.x;
    const int t = threadIdx.x;
    const int tok = dec[b];
    float* xb = x + (size_t)b * (H_ + EMB_);
    for (int i = t; i < H_; i += 256) xb[i] = ctx[(size_t)b * H_ + i];
    for (int i = t; i < EMB_; i += 256) xb[H_ + i] = emb[(size_t)tok * EMB_ + i];
}

// ---------------------------------------------------------------------------
// GRU gates (xm/hm already include their biases): state -> fp32 output region
// ---------------------------------------------------------------------------
__global__ void gates_kernel(const float* __restrict__ xm, const float* __restrict__ hm,
                             const float* __restrict__ hidden,
                             float* __restrict__ state_out) {
    const int idx = blockIdx.x * 256 + threadIdx.x;  // 0..65535
    const int b = idx >> 10, j = idx & (H_ - 1);
    const float* xmb = xm + (size_t)b * 3 * H_;
    const float* hmb = hm + (size_t)b * 3 * H_;
    float z = sigmoidf_(xmb[j] + hmb[j]);
    float r = sigmoidf_(xmb[H_ + j] + hmb[H_ + j]);
    float hc = tanhf(xmb[2 * H_ + j] + r * hmb[2 * H_ + j]);
    state_out[idx] = z * hidden[idx] + (1.0f - z) * hc;
}

// ---------------------------------------------------------------------------
extern "C" void kernel_launch(void* const* d_in, const int* in_sizes, int n_in,
                              void* d_out, int out_size, void* d_ws, size_t ws_size,
                              hipStream_t stream) {
    const int* dec_input = (const int*)d_in[0];
    const float* hidden = (const float*)d_in[1];
    const float* enc = (const float*)d_in[2];
    const float* emb = (const float*)d_in[3];
    const float* W1_k = (const float*)d_in[4];
    const float* W1_b = (const float*)d_in[5];
    const float* W2_k = (const float*)d_in[6];
    const float* W2_b = (const float*)d_in[7];
    const float* V_k = (const float*)d_in[8];
    const float* V_b = (const float*)d_in[9];
    const float* gru_k = (const float*)d_in[10];
    const float* gru_rk = (const float*)d_in[11];
    const float* gru_b = (const float*)d_in[12];
    const float* out_k = (const float*)d_in[13];
    const float* out_b = (const float*)d_in[14];

    float* out = (float*)d_out;
    float* probs_out = out;                              // 64*32000
    float* state_out = out + (size_t)B_ * VOCAB_;        // 64*1024
    float* attn_out = state_out + (size_t)B_ * H_;       // 64*128

    // scratch (floats): hproj 65536 | hm 196608 | score 8192 | ctx 65536 |
    // xvec 98304 | xm 196608  -> 630,784 floats (2.52 MB)
    const size_t NEED_F = 630784;
    float* scratch = (ws_size >= NEED_F * sizeof(float)) ? (float*)d_ws
                                                         : probs_out;  // fallback
    float* hproj = scratch;
    float* hm = hproj + B_ * H_;
    float* score = hm + B_ * 3 * H_;
    float* ctx = score + B_ * S_;
    float* xvec = ctx + B_ * H_;
    float* xm = xvec + B_ * (H_ + EMB_);

    // --- pre-init accumulators with biases (fused, 1 launch) ---
    const int INIT_TOTAL = B_ * H_ + 2 * B_ * 3 * H_ + B_ * S_;  // 466944
    init_bias4_kernel<<<(INIT_TOTAL + 255) / 256, 256, 0, stream>>>(
        hproj, W2_b, hm, xm, gru_b, score, V_b);

    // 1. hproj += hidden @ W2_k   (N=1024: 16 n-tiles x KS=8 -> 128 blocks)
    gemm_mfma_atomic_kernel<1><<<dim3(16, 8), 256, 0, stream>>>(hidden, H_, W2_k, H_,
                                                                hproj, H_ / 8);
    // 2. hm += hidden @ gru_rk    (N=3072: 48 x KS=4 -> 192 blocks)
    gemm_mfma_atomic_kernel<1><<<dim3(48, 4), 256, 0, stream>>>(hidden, H_, gru_rk,
                                                                3 * H_, hm, H_ / 4);
    // 3. score += fused tanh/V epilogue of enc @ W1  (4 n-tiles x 128 m-tiles)
    score_mfma_kernel<<<dim3(4, 128), 256, 0, stream>>>(enc, W1_k, W1_b, V_k, hproj,
                                                        score);
    // 4. softmax -> attn output region
    softmax_kernel<<<B_, S_, 0, stream>>>(score, attn_out);
    // 5. context
    context_kernel<<<B_ * (H_ / 256), 256, 0, stream>>>(attn_out, enc, ctx);
    // 6. x = concat(context, emb[dec])
    buildx_kernel<<<B_, 256, 0, stream>>>(ctx, emb, dec_input, xvec);
    // 7. xm += x @ gru_k          (K=1536: 48 x KS=4 -> 192 blocks)
    gemm_mfma_atomic_kernel<1><<<dim3(48, 4), 256, 0, stream>>>(xvec, H_ + EMB_, gru_k,
                                                                3 * H_, xm, (H_ + EMB_) / 4);
    // 8. gates -> state output region
    gates_kernel<<<(B_ * H_) / 256, 256, 0, stream>>>(xm, hm, hidden, state_out);
    // 9. probs = state @ out_k + out_b  (250 blocks, direct store)
    probs_mfma_kernel<<<dim3(VOCAB_ / 128), 256, 0, stream>>>(state_out, out_k, out_b,
                                                              probs_out);
}

// Round 2
// 374.211 us; speedup vs baseline: 1.6457x; 1.2594x over previous
//
#include <hip/hip_runtime.h>

// Decoder: Bahdanau attention + GRU cell + vocab projection
// VOCAB=32000, EMB=512, H=1024, B=64, S=128
// GEMMs via bf16 MFMA (v_mfma_f32_16x16x32_bf16), fp32 accumulate.
// Fragment layouts (learn_hip m89/m91/m120):
//   A: lane holds A[m=lane&15][k=(lane>>4)*8 + j], j=0..7 (8 bf16, b128)
//   B: lane holds B[k=(lane>>4)*8 + j][n=lane&15]
//   C/D: row=(lane>>4)*4+reg, col=lane&15
//
// R2: latency-bound fix (probs was 111us at 10% occupancy, MfmaUtil 1.4%).
//  - B staged directly as bf16 [k][n] (no fp32 Braw round-trip). Row-chunk
//    XOR swizzle (chunk ^= 2*(k>>3)) makes the 8 ds_read_u16 per B-fragment
//    <=2-way (quads hit 4 disjoint 32B pair-regions).
//  - Reg-staged double-buffered pipeline: ONE barrier per k-step, global
//    loads for k+32 issued before the MFMA phase (in flight ~1 iteration).
//  - probs: NF=1 -> 500 blocks (2/CU); hm/xm/hproj k-split x8.

#define B_ 64
#define S_ 128
#define H_ 1024
#define EMB_ 512
#define VOCAB_ 32000

typedef __attribute__((ext_vector_type(8))) short short8;
typedef __attribute__((ext_vector_type(4))) float f32x4;

__device__ __forceinline__ unsigned short f2bf_bits(float f) {
    unsigned int u = __float_as_uint(f);
    u += 0x7FFF + ((u >> 16) & 1);  // round-to-nearest-even
    return (unsigned short)(u >> 16);
}
__device__ __forceinline__ float sigmoidf_(float x) { return 1.0f / (1.0f + expf(-x)); }
// A-tile swizzle key (16B slots within a 64B row of 32 bf16)
__device__ __forceinline__ int sw_(int r) { return (r ^ (r >> 2)) & 3; }
// B-tile swizzle key for k-row: shifts chunk PAIR index so the 4 quads of a
// fragment-read instruction (k = quad*8+j) hit 4 disjoint 32B regions.
__device__ __forceinline__ int bsw_(int k) { return ((k >> 3) & 3) << 1; }

__device__ __forceinline__ short8 pack8_(float4 lo, float4 hi) {
    short8 s;
    s[0] = (short)f2bf_bits(lo.x);
    s[1] = (short)f2bf_bits(lo.y);
    s[2] = (short)f2bf_bits(lo.z);
    s[3] = (short)f2bf_bits(lo.w);
    s[4] = (short)f2bf_bits(hi.x);
    s[5] = (short)f2bf_bits(hi.y);
    s[6] = (short)f2bf_bits(hi.z);
    s[7] = (short)f2bf_bits(hi.w);
    return s;
}

// ---------------------------------------------------------------------------
// Tile GEMM core: C_tile(64 x 64*NF) += A(64xK slice) * W(K x N) over k0..k1.
// A fp32 row-major (lda), W fp32 row-major (ldw). bf16 conversion on the fly.
// Block = 256 threads = 4 waves; wave w covers cols [w*16*NF, (w+1)*16*NF).
// Double-buffered LDS, reg-staged prefetch, one barrier per 32-k step.
// ---------------------------------------------------------------------------
template <int NF>
__device__ void mfma_gemm_tile(const float* __restrict__ A, int lda,
                               const float* __restrict__ W, int ldw,
                               int m_base, int n_base, int k0, int k1,
                               f32x4 (&acc)[4][NF]) {
    constexpr int NT = 64 * NF;   // tile cols
    constexpr int CPR = NT / 8;   // 16B chunks per B k-row
    __shared__ __attribute__((aligned(16))) unsigned short A_lds[2][64 * 32];
    __shared__ __attribute__((aligned(16))) unsigned short B_lds[2][32 * NT];
    const int tid = threadIdx.x;
    const int w = tid >> 6, lane = tid & 63, quad = lane >> 4, l15 = lane & 15;

    const f32x4 z = {0.0f, 0.0f, 0.0f, 0.0f};
#pragma unroll
    for (int mi = 0; mi < 4; ++mi)
#pragma unroll
        for (int ni = 0; ni < NF; ++ni) acc[mi][ni] = z;

    // A staging coords: row ar, 16B k-chunk ac
    const int ar = tid >> 2, ac = tid & 3;
    const int aslot = ac ^ sw_(ar);
    // B staging coords: each job = 8 consecutive n in one k-row
    int bkr[NF], bch[NF];
#pragma unroll
    for (int i = 0; i < NF; ++i) {
        int id = tid + 256 * i;
        bkr[i] = id / CPR;
        bch[i] = id % CPR;
    }

    float4 a0, a1, blo[NF], bhi[NF];
    {  // prologue: load tile k0 into registers
        const float* asrc = A + (size_t)(m_base + ar) * lda + k0 + 8 * ac;
        a0 = *(const float4*)asrc;
        a1 = *(const float4*)(asrc + 4);
#pragma unroll
        for (int i = 0; i < NF; ++i) {
            const float* bs = W + (size_t)(k0 + bkr[i]) * ldw + n_base + 8 * bch[i];
            blo[i] = *(const float4*)bs;
            bhi[i] = *(const float4*)(bs + 4);
        }
    }

    int p = 0;
    for (int k = k0; k < k1; k += 32) {
        // ---- convert + write current tile to LDS buf p ----
        *(short8*)&A_lds[p][ar * 32 + aslot * 8] = pack8_(a0, a1);
#pragma unroll
        for (int i = 0; i < NF; ++i)
            *(short8*)&B_lds[p][bkr[i] * NT + ((bch[i] ^ bsw_(bkr[i])) << 3)] =
                pack8_(blo[i], bhi[i]);
        __syncthreads();
        // ---- issue next-tile global loads (in flight across MFMA phase) ----
        if (k + 32 < k1) {
            const float* asrc = A + (size_t)(m_base + ar) * lda + (k + 32) + 8 * ac;
            a0 = *(const float4*)asrc;
            a1 = *(const float4*)(asrc + 4);
#pragma unroll
            for (int i = 0; i < NF; ++i) {
                const float* bs =
                    W + (size_t)(k + 32 + bkr[i]) * ldw + n_base + 8 * bch[i];
                blo[i] = *(const float4*)bs;
                bhi[i] = *(const float4*)(bs + 4);
            }
        }
        // ---- B fragments: 8 ds_read_u16, quads spread via bsw_ ----
        short8 bfrag[NF];
#pragma unroll
        for (int ni = 0; ni < NF; ++ni) {
            int nrel = w * 16 * NF + 16 * ni + l15;
            int ch = nrel >> 3, off = nrel & 7;
#pragma unroll
            for (int j = 0; j < 8; ++j) {
                int kk = quad * 8 + j;
                bfrag[ni][j] =
                    (short)B_lds[p][kk * NT + (((ch ^ bsw_(kk)) << 3) + off)];
            }
        }
        // ---- A fragments + MFMA ----
#pragma unroll
        for (int mi = 0; mi < 4; ++mi) {
            int r = 16 * mi + l15;
            short8 afrag = *(const short8*)&A_lds[p][r * 32 + ((quad ^ sw_(r)) << 3)];
#pragma unroll
            for (int ni = 0; ni < NF; ++ni)
                acc[mi][ni] = __builtin_amdgcn_mfma_f32_16x16x32_bf16(
                    afrag, bfrag[ni], acc[mi][ni], 0, 0, 0);
        }
        p ^= 1;
        // no trailing barrier: next iter writes the OTHER buffer; same-buffer
        // reuse is ordered by the next iteration's barrier.
    }
}

// ---------------------------------------------------------------------------
// Fused bias pre-init for all atomic-accumulate targets.
// Segments: hproj[B*H] | hm[B*3H] | xm[B*3H] | score[B*S]
// ---------------------------------------------------------------------------
__global__ void init_bias4_kernel(float* __restrict__ hproj, const float* __restrict__ W2_b,
                                  float* __restrict__ hm, float* __restrict__ xm,
                                  const float* __restrict__ gru_b,
                                  float* __restrict__ score, const float* __restrict__ V_b) {
    int i = blockIdx.x * 256 + threadIdx.x;
    const int E0 = B_ * H_;
    const int E1 = E0 + B_ * 3 * H_;
    const int E2 = E1 + B_ * 3 * H_;
    const int E3 = E2 + B_ * S_;
    if (i < E0) {
        hproj[i] = W2_b[i & (H_ - 1)];
    } else if (i < E1) {
        int j = i - E0;
        hm[j] = gru_b[3 * H_ + j % (3 * H_)];
    } else if (i < E2) {
        int j = i - E1;
        xm[j] = gru_b[j % (3 * H_)];
    } else if (i < E3) {
        score[i - E2] = V_b[0];
    }
}

// ---------------------------------------------------------------------------
// Skinny GEMM (M=64), K-split across blockIdx.y, atomicAdd into pre-inited C.
// ---------------------------------------------------------------------------
template <int NF>
__global__ __launch_bounds__(256) void gemm_mfma_atomic_kernel(
    const float* __restrict__ A, int lda, const float* __restrict__ W, int ldw,
    float* __restrict__ C, int kslice) {
    f32x4 acc[4][NF];
    const int n_base = blockIdx.x * 64 * NF;
    const int k0 = blockIdx.y * kslice;
    mfma_gemm_tile<NF>(A, lda, W, ldw, 0, n_base, k0, k0 + kslice, acc);
    const int tid = threadIdx.x, w = tid >> 6, lane = tid & 63;
    const int quad = lane >> 4, l15 = lane & 15;
#pragma unroll
    for (int mi = 0; mi < 4; ++mi)
#pragma unroll
        for (int ni = 0; ni < NF; ++ni) {
            int col = n_base + w * 16 * NF + 16 * ni + l15;
#pragma unroll
            for (int r = 0; r < 4; ++r) {
                int row = 16 * mi + quad * 4 + r;
                atomicAdd(&C[(size_t)row * ldw + col], acc[mi][ni][r]);
            }
        }
}

// ---------------------------------------------------------------------------
// score: feat = enc @ W1 (block: 64 (b,s)-rows x 256 feat-cols), then
// partial score = sum_k tanh(feat + W1b[k] + hproj[b][k]) * Vk[k], reduced
// across the 16 lanes sharing a quad, atomicAdd into V_b-pre-inited score.
// ---------------------------------------------------------------------------
__global__ __launch_bounds__(256) void score_mfma_kernel(
    const float* __restrict__ enc, const float* __restrict__ W1,
    const float* __restrict__ W1b, const float* __restrict__ Vk,
    const float* __restrict__ hproj, float* __restrict__ score) {
    f32x4 acc[4][4];
    const int n_base = blockIdx.x * 256;
    const int m_base = blockIdx.y * 64;
    const int b = m_base >> 7, s_base = m_base & 127;
    mfma_gemm_tile<4>(enc, H_, W1, H_, m_base, n_base, 0, H_, acc);

    const int tid = threadIdx.x, w = tid >> 6, lane = tid & 63;
    const int quad = lane >> 4, l15 = lane & 15;

    float rowpart[4][4];
#pragma unroll
    for (int mi = 0; mi < 4; ++mi)
#pragma unroll
        for (int r = 0; r < 4; ++r) rowpart[mi][r] = 0.0f;

#pragma unroll
    for (int ni = 0; ni < 4; ++ni) {
        int kcol = n_base + w * 64 + 16 * ni + l15;
        float add = W1b[kcol] + hproj[(size_t)b * H_ + kcol];
        float vv = Vk[kcol];
#pragma unroll
        for (int mi = 0; mi < 4; ++mi)
#pragma unroll
            for (int r = 0; r < 4; ++r)
                rowpart[mi][r] += tanhf(acc[mi][ni][r] + add) * vv;
    }
    // reduce across the 16 lanes with the same quad (xor over bits 0..3)
#pragma unroll
    for (int m = 1; m <= 8; m <<= 1)
#pragma unroll
        for (int mi = 0; mi < 4; ++mi)
#pragma unroll
            for (int r = 0; r < 4; ++r)
                rowpart[mi][r] += __shfl_xor(rowpart[mi][r], m, 64);
    if (l15 == 0) {
#pragma unroll
        for (int mi = 0; mi < 4; ++mi)
#pragma unroll
            for (int r = 0; r < 4; ++r)
                atomicAdd(&score[b * S_ + s_base + 16 * mi + quad * 4 + r],
                          rowpart[mi][r]);
    }
}

// ---------------------------------------------------------------------------
// probs = state @ out_k + out_b (M=64, N=32000, K=1024), direct store.
// NF=1 -> 500 blocks for occupancy.
// ---------------------------------------------------------------------------
__global__ __launch_bounds__(256) void probs_mfma_kernel(
    const float* __restrict__ state, const float* __restrict__ out_k,
    const float* __restrict__ out_b, float* __restrict__ probs) {
    f32x4 acc[4][1];
    const int n_base = blockIdx.x * 64;
    mfma_gemm_tile<1>(state, H_, out_k, VOCAB_, 0, n_base, 0, H_, acc);
    const int tid = threadIdx.x, w = tid >> 6, lane = tid & 63;
    const int quad = lane >> 4, l15 = lane & 15;
    int col = n_base + w * 16 + l15;
    float bv = out_b[col];
#pragma unroll
    for (int mi = 0; mi < 4; ++mi) {
#pragma unroll
        for (int r = 0; r < 4; ++r) {
            int row = 16 * mi + quad * 4 + r;
            probs[(size_t)row * VOCAB_ + col] = acc[mi][0][r] + bv;
        }
    }
}

// ---------------------------------------------------------------------------
// softmax over S per batch -> fp32 attn output region
// ---------------------------------------------------------------------------
__global__ void softmax_kernel(const float* __restrict__ score,
                               float* __restrict__ attn_out) {
    const int b = blockIdx.x;
    const int s = threadIdx.x;  // 128 threads
    __shared__ float red[128];
    float v = score[b * S_ + s];
    red[s] = v;
    __syncthreads();
    for (int str = 64; str > 0; str >>= 1) {
        if (s < str) red[s] = fmaxf(red[s], red[s + str]);
        __syncthreads();
    }
    float m = red[0];
    __syncthreads();
    float e = expf(v - m);
    red[s] = e;
    __syncthreads();
    for (int str = 64; str > 0; str >>= 1) {
        if (s < str) red[s] += red[s + str];
        __syncthreads();
    }
    attn_out[b * S_ + s] = e / red[0];
}

// ---------------------------------------------------------------------------
// context[b,h] = sum_s attn[b,s] * enc[b,s,h]  (4-way unrolled for MLP)
// ---------------------------------------------------------------------------
__global__ void context_kernel(const float* __restrict__ attn,
                               const float* __restrict__ enc,
                               float* __restrict__ ctx) {
    const int b = blockIdx.x >> 2;
    const int h = ((blockIdx.x & 3) << 8) + threadIdx.x;
    __shared__ float aw[S_];
    if (threadIdx.x < S_) aw[threadIdx.x] = attn[b * S_ + threadIdx.x];
    __syncthreads();
    const float* ebase = enc + (size_t)b * S_ * H_ + h;
    float a0 = 0.0f, a1 = 0.0f, a2 = 0.0f, a3 = 0.0f;
#pragma unroll 4
    for (int s = 0; s < S_; s += 4) {
        a0 += aw[s + 0] * ebase[(size_t)(s + 0) * H_];
        a1 += aw[s + 1] * ebase[(size_t)(s + 1) * H_];
        a2 += aw[s + 2] * ebase[(size_t)(s + 2) * H_];
        a3 += aw[s + 3] * ebase[(size_t)(s + 3) * H_];
    }
    ctx[(size_t)b * H_ + h] = (a0 + a1) + (a2 + a3);
}

// ---------------------------------------------------------------------------
// x[b,:] = concat(context[b,:], emb[dec[b],:])
// ---------------------------------------------------------------------------
__global__ void buildx_kernel(const float* __restrict__ ctx, const float* __restrict__ emb,
                              const int* __restrict__ dec, float* __restrict__ x) {
    const int b = blockIdx.x;
    const int t = threadIdx.x;
    const int tok = dec[b];
    float* xb = x + (size_t)b * (H_ + EMB_);
    for (int i = t; i < H_; i += 256) xb[i] = ctx[(size_t)b * H_ + i];
    for (int i = t; i < EMB_; i += 256) xb[H_ + i] = emb[(size_t)tok * EMB_ + i];
}

// ---------------------------------------------------------------------------
// GRU gates (xm/hm already include their biases): state -> fp32 output region
// ---------------------------------------------------------------------------
__global__ void gates_kernel(const float* __restrict__ xm, const float* __restrict__ hm,
                             const float* __restrict__ hidden,
                             float* __restrict__ state_out) {
    const int idx = blockIdx.x * 256 + threadIdx.x;  // 0..65535
    const int b = idx >> 10, j = idx & (H_ - 1);
    const float* xmb = xm + (size_t)b * 3 * H_;
    const float* hmb = hm + (size_t)b * 3 * H_;
    float z = sigmoidf_(xmb[j] + hmb[j]);
    float r = sigmoidf_(xmb[H_ + j] + hmb[H_ + j]);
    float hc = tanhf(xmb[2 * H_ + j] + r * hmb[2 * H_ + j]);
    state_out[idx] = z * hidden[idx] + (1.0f - z) * hc;
}

// ---------------------------------------------------------------------------
extern "C" void kernel_launch(void* const* d_in, const int* in_sizes, int n_in,
                              void* d_out, int out_size, void* d_ws, size_t ws_size,
                              hipStream_t stream) {
    const int* dec_input = (const int*)d_in[0];
    const float* hidden = (const float*)d_in[1];
    const float* enc = (const float*)d_in[2];
    const float* emb = (const float*)d_in[3];
    const float* W1_k = (const float*)d_in[4];
    const float* W1_b = (const float*)d_in[5];
    const float* W2_k = (const float*)d_in[6];
    const float* W2_b = (const float*)d_in[7];
    const float* V_k = (const float*)d_in[8];
    const float* V_b = (const float*)d_in[9];
    const float* gru_k = (const float*)d_in[10];
    const float* gru_rk = (const float*)d_in[11];
    const float* gru_b = (const float*)d_in[12];
    const float* out_k = (const float*)d_in[13];
    const float* out_b = (const float*)d_in[14];

    float* out = (float*)d_out;
    float* probs_out = out;                              // 64*32000
    float* state_out = out + (size_t)B_ * VOCAB_;        // 64*1024
    float* attn_out = state_out + (size_t)B_ * H_;       // 64*128

    // scratch (floats): hproj 65536 | hm 196608 | score 8192 | ctx 65536 |
    // xvec 98304 | xm 196608  -> 630,784 floats (2.52 MB)
    const size_t NEED_F = 630784;
    float* scratch = (ws_size >= NEED_F * sizeof(float)) ? (float*)d_ws
                                                         : probs_out;  // fallback
    float* hproj = scratch;
    float* hm = hproj + B_ * H_;
    float* score = hm + B_ * 3 * H_;
    float* ctx = score + B_ * S_;
    float* xvec = ctx + B_ * H_;
    float* xm = xvec + B_ * (H_ + EMB_);

    // --- pre-init accumulators with biases (fused, 1 launch) ---
    const int INIT_TOTAL = B_ * H_ + 2 * B_ * 3 * H_ + B_ * S_;  // 466944
    init_bias4_kernel<<<(INIT_TOTAL + 255) / 256, 256, 0, stream>>>(
        hproj, W2_b, hm, xm, gru_b, score, V_b);

    // 1. hproj += hidden @ W2_k   (16 n-tiles x KS=8 -> 128 blocks, 4 k-steps)
    gemm_mfma_atomic_kernel<1><<<dim3(16, 8), 256, 0, stream>>>(hidden, H_, W2_k, H_,
                                                                hproj, H_ / 8);
    // 2. hm += hidden @ gru_rk    (48 x 8 -> 384 blocks, 4 k-steps)
    gemm_mfma_atomic_kernel<1><<<dim3(48, 8), 256, 0, stream>>>(hidden, H_, gru_rk,
                                                                3 * H_, hm, H_ / 8);
    // 3. score += fused tanh/V epilogue of enc @ W1  (4 n-tiles x 128 m-tiles)
    score_mfma_kernel<<<dim3(4, 128), 256, 0, stream>>>(enc, W1_k, W1_b, V_k, hproj,
                                                        score);
    // 4. softmax -> attn output region
    softmax_kernel<<<B_, S_, 0, stream>>>(score, attn_out);
    // 5. context
    context_kernel<<<B_ * (H_ / 256), 256, 0, stream>>>(attn_out, enc, ctx);
    // 6. x = concat(context, emb[dec])
    buildx_kernel<<<B_, 256, 0, stream>>>(ctx, emb, dec_input, xvec);
    // 7. xm += x @ gru_k          (48 x 8 -> 384 blocks, 6 k-steps)
    gemm_mfma_atomic_kernel<1><<<dim3(48, 8), 256, 0, stream>>>(xvec, H_ + EMB_, gru_k,
                                                                3 * H_, xm, (H_ + EMB_) / 8);
    // 8. gates -> state output region
    gates_kernel<<<(B_ * H_) / 256, 256, 0, stream>>>(xm, hm, hidden, state_out);
    // 9. probs = state @ out_k + out_b  (500 blocks, NF=1, direct store)
    probs_mfma_kernel<<<dim3(VOCAB_ / 64), 256, 0, stream>>>(state_out, out_k, out_b,
                                                             probs_out);
}

// Round 3
// 368.398 us; speedup vs baseline: 1.6717x; 1.0158x over previous
//
#include <hip/hip_runtime.h>

// Decoder: Bahdanau attention + GRU cell + vocab projection
// VOCAB=32000, EMB=512, H=1024, B=64, S=128
// GEMMs via bf16 MFMA (v_mfma_f32_16x16x32_bf16), fp32 accumulate.
// Fragment layouts (learn_hip m89/m91/m120):
//   A: lane holds A[m=lane&15][k=(lane>>4)*8 + j], j=0..7 (8 bf16, b128)
//   B: lane holds B[k=(lane>>4)*8 + j][n=lane&15]
//   C/D: row=(lane>>4)*4+reg, col=lane&15
//
// R3:
//  - Scratch lives in the probs output region; d_ws untouched (the harness's
//    500 MiB workspace poison fill was 76us = 20% of the measured window).
//  - B staged as [n][k] bf16 via per-thread 4x4 in-register transpose
//    (4 coalesced float4 row loads -> 4 swizzled ds_write_b64). B-fragment
//    read is ONE ds_read_b128 (was 8 scalar ds_read_u16).
//  - 2-deep register prefetch (two named sets, loop unrolled x2), one
//    barrier per 32-k step.
//  - Fused attn_ctx kernel (softmax+context+buildx); fused hproj+hm dual
//    GEMM launch. 7 launches total.

#define B_ 64
#define S_ 128
#define H_ 1024
#define EMB_ 512
#define VOCAB_ 32000

typedef __attribute__((ext_vector_type(8))) short short8;
typedef __attribute__((ext_vector_type(4))) float f32x4;

__device__ __forceinline__ unsigned short f2bf_bits(float f) {
    unsigned int u = __float_as_uint(f);
    u += 0x7FFF + ((u >> 16) & 1);  // round-to-nearest-even
    return (unsigned short)(u >> 16);
}
__device__ __forceinline__ float sigmoidf_(float x) { return 1.0f / (1.0f + expf(-x)); }
// A-tile swizzle key (16B slots within a 64B row of 32 bf16)
__device__ __forceinline__ int sw_(int r) { return (r ^ (r >> 2)) & 3; }
// B-tile swizzle key for col n (16B chunk XOR within [n][32k] row)
__device__ __forceinline__ int bf_(int n) { return (n ^ (n >> 2)) & 3; }
__device__ __forceinline__ float fc4_(const float4& v, int c) {
    return c == 0 ? v.x : c == 1 ? v.y : c == 2 ? v.z : v.w;
}

__device__ __forceinline__ short8 pack8_(float4 lo, float4 hi) {
    short8 s;
    s[0] = (short)f2bf_bits(lo.x);
    s[1] = (short)f2bf_bits(lo.y);
    s[2] = (short)f2bf_bits(lo.z);
    s[3] = (short)f2bf_bits(lo.w);
    s[4] = (short)f2bf_bits(hi.x);
    s[5] = (short)f2bf_bits(hi.y);
    s[6] = (short)f2bf_bits(hi.z);
    s[7] = (short)f2bf_bits(hi.w);
    return s;
}

// ---------------------------------------------------------------------------
// Tile GEMM core: C_tile(64 x 64*NF) += A(64xK slice) * W(K x N) over k0..k1.
// Requires (k1-k0)/32 even (all call sites: 4, 6, or 32 steps).
// A_lds: [64 m][32 k] bf16, 16B-slot swizzle sw_(row).
// B_lds: [NT n][32 k] bf16, element [n][k] at n*32 + ((k>>3)^bf_(n))*8 + (k&7).
// ---------------------------------------------------------------------------
template <int NF>
__device__ void mfma_gemm_tile(const float* __restrict__ A, int lda,
                               const float* __restrict__ W, int ldw,
                               int m_base, int n_base, int k0, int k1,
                               f32x4 (&acc)[4][NF]) {
    constexpr int NT = 64 * NF;
    constexpr int JOBS = (NF >= 2) ? NF / 2 : 1;
    __shared__ __attribute__((aligned(16))) unsigned short A_lds[2][64 * 32];
    __shared__ __attribute__((aligned(16))) unsigned short B_lds[2][NT * 32];
    const int tid = threadIdx.x;
    const int w = tid >> 6, lane = tid & 63, quad = lane >> 4, l15 = lane & 15;

    const f32x4 z = {0.0f, 0.0f, 0.0f, 0.0f};
#pragma unroll
    for (int mi = 0; mi < 4; ++mi)
#pragma unroll
        for (int ni = 0; ni < NF; ++ni) acc[mi][ni] = z;

    // A staging coords: row ar, 16B k-chunk ac
    const int ar = tid >> 2, ac = tid & 3;
    const int aslot = ac ^ sw_(ar);
    // B staging jobs: 4k x 4n blocks (NF>=2) or 4k x 2n (NF==1)
    int bk[JOBS], bn[JOBS];
    if constexpr (NF == 1) {
        bk[0] = 4 * (tid >> 5);  // 0,4,..,28
        bn[0] = 2 * (tid & 31);  // 0,2,..,62
    } else {
#pragma unroll
        for (int j = 0; j < JOBS; ++j) {
            int id = tid + 256 * j;
            bk[j] = 4 * (id / (16 * NF));
            bn[j] = 4 * (id % (16 * NF));
        }
    }

    float4 areg[2][2];
    float4 br4[2][JOBS][4];  // NF>=2
    float2 br2[2][4];        // NF==1

    // ---- prologue: load tile sets 0 and 1 ----
#pragma unroll
    for (int s = 0; s < 2; ++s) {
        int kk = k0 + 32 * s;
        if (s == 0 || kk < k1) {
            const float* asrc = A + (size_t)(m_base + ar) * lda + kk + 8 * ac;
            areg[s][0] = *(const float4*)asrc;
            areg[s][1] = *(const float4*)(asrc + 4);
            if constexpr (NF == 1) {
                const float* bs = W + (size_t)(kk + bk[0]) * ldw + n_base + bn[0];
#pragma unroll
                for (int i = 0; i < 4; ++i)
                    br2[s][i] = *(const float2*)(bs + (size_t)i * ldw);
            } else {
#pragma unroll
                for (int j = 0; j < JOBS; ++j) {
                    const float* bs = W + (size_t)(kk + bk[j]) * ldw + n_base + bn[j];
#pragma unroll
                    for (int i = 0; i < 4; ++i)
                        br4[s][j][i] = *(const float4*)(bs + (size_t)i * ldw);
                }
            }
        }
    }

    int p = 0;
    for (int k = k0; k < k1; k += 64) {
#pragma unroll
        for (int s = 0; s < 2; ++s) {
            const int kk = k + 32 * s;
            // ---- convert + write set s -> LDS[p] ----
            *(short8*)&A_lds[p][ar * 32 + aslot * 8] = pack8_(areg[s][0], areg[s][1]);
            if constexpr (NF == 1) {
                const int kb = bk[0];
#pragma unroll
                for (int c = 0; c < 2; ++c) {
                    int n = bn[0] + c;
                    int si = n * 32 + ((((kb >> 3) ^ bf_(n)) << 3) + (kb & 7));
                    unsigned int lo, hi;
                    if (c == 0) {
                        lo = (unsigned)f2bf_bits(br2[s][0].x) |
                             ((unsigned)f2bf_bits(br2[s][1].x) << 16);
                        hi = (unsigned)f2bf_bits(br2[s][2].x) |
                             ((unsigned)f2bf_bits(br2[s][3].x) << 16);
                    } else {
                        lo = (unsigned)f2bf_bits(br2[s][0].y) |
                             ((unsigned)f2bf_bits(br2[s][1].y) << 16);
                        hi = (unsigned)f2bf_bits(br2[s][2].y) |
                             ((unsigned)f2bf_bits(br2[s][3].y) << 16);
                    }
                    uint2 wv;
                    wv.x = lo;
                    wv.y = hi;
                    *(uint2*)&B_lds[p][si] = wv;
                }
            } else {
#pragma unroll
                for (int j = 0; j < JOBS; ++j) {
                    const int kb = bk[j];
#pragma unroll
                    for (int c = 0; c < 4; ++c) {
                        int n = bn[j] + c;
                        int si = n * 32 + ((((kb >> 3) ^ bf_(n)) << 3) + (kb & 7));
                        unsigned int lo = (unsigned)f2bf_bits(fc4_(br4[s][j][0], c)) |
                                          ((unsigned)f2bf_bits(fc4_(br4[s][j][1], c)) << 16);
                        unsigned int hi = (unsigned)f2bf_bits(fc4_(br4[s][j][2], c)) |
                                          ((unsigned)f2bf_bits(fc4_(br4[s][j][3], c)) << 16);
                        uint2 wv;
                        wv.x = lo;
                        wv.y = hi;
                        *(uint2*)&B_lds[p][si] = wv;
                    }
                }
            }
            __syncthreads();
            // ---- prefetch set s <- tile kk+64 (2 tiles ahead) ----
            const int kpre = kk + 64;
            if (kpre < k1) {
                const float* asrc = A + (size_t)(m_base + ar) * lda + kpre + 8 * ac;
                areg[s][0] = *(const float4*)asrc;
                areg[s][1] = *(const float4*)(asrc + 4);
                if constexpr (NF == 1) {
                    const float* bs = W + (size_t)(kpre + bk[0]) * ldw + n_base + bn[0];
#pragma unroll
                    for (int i = 0; i < 4; ++i)
                        br2[s][i] = *(const float2*)(bs + (size_t)i * ldw);
                } else {
#pragma unroll
                    for (int j = 0; j < JOBS; ++j) {
                        const float* bs =
                            W + (size_t)(kpre + bk[j]) * ldw + n_base + bn[j];
#pragma unroll
                        for (int i = 0; i < 4; ++i)
                            br4[s][j][i] = *(const float4*)(bs + (size_t)i * ldw);
                    }
                }
            }
            // ---- compute tile kk from LDS[p] ----
            short8 bfrag[NF];
#pragma unroll
            for (int ni = 0; ni < NF; ++ni) {
                int nrel = w * 16 * NF + 16 * ni + l15;
                bfrag[ni] =
                    *(const short8*)&B_lds[p][nrel * 32 + ((quad ^ bf_(nrel)) << 3)];
            }
#pragma unroll
            for (int mi = 0; mi < 4; ++mi) {
                int r = 16 * mi + l15;
                short8 afrag =
                    *(const short8*)&A_lds[p][r * 32 + ((quad ^ sw_(r)) << 3)];
#pragma unroll
                for (int ni = 0; ni < NF; ++ni)
                    acc[mi][ni] = __builtin_amdgcn_mfma_f32_16x16x32_bf16(
                        afrag, bfrag[ni], acc[mi][ni], 0, 0, 0);
            }
            p ^= 1;
        }
    }
}

// ---------------------------------------------------------------------------
// Fused bias pre-init for all atomic-accumulate targets.
// Scratch layout: hproj[B*H] | hm[B*3H] | score[B*S] | xvec[B*(H+EMB)] | xm[B*3H]
// ---------------------------------------------------------------------------
__global__ void init_bias4_kernel(float* __restrict__ hproj, const float* __restrict__ W2_b,
                                  float* __restrict__ hm, float* __restrict__ xm,
                                  const float* __restrict__ gru_b,
                                  float* __restrict__ score, const float* __restrict__ V_b) {
    int i = blockIdx.x * 256 + threadIdx.x;
    const int E0 = B_ * H_;
    const int E1 = E0 + B_ * 3 * H_;
    const int E2 = E1 + B_ * 3 * H_;
    const int E3 = E2 + B_ * S_;
    if (i < E0) {
        hproj[i] = W2_b[i & (H_ - 1)];
    } else if (i < E1) {
        int j = i - E0;
        hm[j] = gru_b[3 * H_ + j % (3 * H_)];
    } else if (i < E2) {
        int j = i - E1;
        xm[j] = gru_b[j % (3 * H_)];
    } else if (i < E3) {
        score[i - E2] = V_b[0];
    }
}

// ---------------------------------------------------------------------------
// Skinny GEMM (M=64), K-split across blockIdx.y, atomicAdd into pre-inited C.
// ---------------------------------------------------------------------------
template <int NF>
__global__ __launch_bounds__(256) void gemm_mfma_atomic_kernel(
    const float* __restrict__ A, int lda, const float* __restrict__ W, int ldw,
    float* __restrict__ C, int kslice) {
    f32x4 acc[4][NF];
    const int n_base = blockIdx.x * 64 * NF;
    const int k0 = blockIdx.y * kslice;
    mfma_gemm_tile<NF>(A, lda, W, ldw, 0, n_base, k0, k0 + kslice, acc);
    const int tid = threadIdx.x, w = tid >> 6, lane = tid & 63;
    const int quad = lane >> 4, l15 = lane & 15;
#pragma unroll
    for (int mi = 0; mi < 4; ++mi)
#pragma unroll
        for (int ni = 0; ni < NF; ++ni) {
            int col = n_base + w * 16 * NF + 16 * ni + l15;
#pragma unroll
            for (int r = 0; r < 4; ++r) {
                int row = 16 * mi + quad * 4 + r;
                atomicAdd(&C[(size_t)row * ldw + col], acc[mi][ni][r]);
            }
        }
}

// ---------------------------------------------------------------------------
// Dual skinny GEMM sharing A=hidden: bx<16 -> hproj += hidden@W2_k (N=1024);
// bx>=16 -> hm += hidden@gru_rk (N=3072). K=1024, k-split via blockIdx.y.
// ---------------------------------------------------------------------------
__global__ __launch_bounds__(256) void gemm_dual_kernel(
    const float* __restrict__ hidden, const float* __restrict__ W2_k,
    const float* __restrict__ gru_rk, float* __restrict__ hproj,
    float* __restrict__ hm, int kslice) {
    f32x4 acc[4][1];
    const int bx = blockIdx.x;
    const float* W;
    float* C;
    int ldw, n_base;
    if (bx < 16) {
        W = W2_k; C = hproj; ldw = H_; n_base = bx * 64;
    } else {
        W = gru_rk; C = hm; ldw = 3 * H_; n_base = (bx - 16) * 64;
    }
    const int k0 = blockIdx.y * kslice;
    mfma_gemm_tile<1>(hidden, H_, W, ldw, 0, n_base, k0, k0 + kslice, acc);
    const int tid = threadIdx.x, w = tid >> 6, lane = tid & 63;
    const int quad = lane >> 4, l15 = lane & 15;
#pragma unroll
    for (int mi = 0; mi < 4; ++mi) {
        int col = n_base + w * 16 + l15;
#pragma unroll
        for (int r = 0; r < 4; ++r) {
            int row = 16 * mi + quad * 4 + r;
            atomicAdd(&C[(size_t)row * ldw + col], acc[mi][0][r]);
        }
    }
}

// ---------------------------------------------------------------------------
// score: feat = enc @ W1 (block: 64 (b,s)-rows x 256 feat-cols), then
// partial score = sum_k tanh(feat + W1b[k] + hproj[b][k]) * Vk[k], reduced
// across the 16 lanes sharing a quad, atomicAdd into V_b-pre-inited score.
// ---------------------------------------------------------------------------
__global__ __launch_bounds__(256) void score_mfma_kernel(
    const float* __restrict__ enc, const float* __restrict__ W1,
    const float* __restrict__ W1b, const float* __restrict__ Vk,
    const float* __restrict__ hproj, float* __restrict__ score) {
    f32x4 acc[4][4];
    const int n_base = blockIdx.x * 256;
    const int m_base = blockIdx.y * 64;
    const int b = m_base >> 7, s_base = m_base & 127;
    mfma_gemm_tile<4>(enc, H_, W1, H_, m_base, n_base, 0, H_, acc);

    const int tid = threadIdx.x, w = tid >> 6, lane = tid & 63;
    const int quad = lane >> 4, l15 = lane & 15;

    float rowpart[4][4];
#pragma unroll
    for (int mi = 0; mi < 4; ++mi)
#pragma unroll
        for (int r = 0; r < 4; ++r) rowpart[mi][r] = 0.0f;

#pragma unroll
    for (int ni = 0; ni < 4; ++ni) {
        int kcol = n_base + w * 64 + 16 * ni + l15;
        float add = W1b[kcol] + hproj[(size_t)b * H_ + kcol];
        float vv = Vk[kcol];
#pragma unroll
        for (int mi = 0; mi < 4; ++mi)
#pragma unroll
            for (int r = 0; r < 4; ++r)
                rowpart[mi][r] += tanhf(acc[mi][ni][r] + add) * vv;
    }
#pragma unroll
    for (int m = 1; m <= 8; m <<= 1)
#pragma unroll
        for (int mi = 0; mi < 4; ++mi)
#pragma unroll
            for (int r = 0; r < 4; ++r)
                rowpart[mi][r] += __shfl_xor(rowpart[mi][r], m, 64);
    if (l15 == 0) {
#pragma unroll
        for (int mi = 0; mi < 4; ++mi)
#pragma unroll
            for (int r = 0; r < 4; ++r)
                atomicAdd(&score[b * S_ + s_base + 16 * mi + quad * 4 + r],
                          rowpart[mi][r]);
    }
}

// ---------------------------------------------------------------------------
// probs = state @ out_k + out_b (M=64, N=32000, K=1024), direct store.
// ---------------------------------------------------------------------------
__global__ __launch_bounds__(256) void probs_mfma_kernel(
    const float* __restrict__ state, const float* __restrict__ out_k,
    const float* __restrict__ out_b, float* __restrict__ probs) {
    f32x4 acc[4][1];
    const int n_base = blockIdx.x * 64;
    mfma_gemm_tile<1>(state, H_, out_k, VOCAB_, 0, n_base, 0, H_, acc);
    const int tid = threadIdx.x, w = tid >> 6, lane = tid & 63;
    const int quad = lane >> 4, l15 = lane & 15;
    int col = n_base + w * 16 + l15;
    float bv = out_b[col];
#pragma unroll
    for (int mi = 0; mi < 4; ++mi) {
#pragma unroll
        for (int r = 0; r < 4; ++r) {
            int row = 16 * mi + quad * 4 + r;
            probs[(size_t)row * VOCAB_ + col] = acc[mi][0][r] + bv;
        }
    }
}

// ---------------------------------------------------------------------------
// Fused softmax + context + buildx. Grid 256 = 64 b x 4 q.
// Each block: softmax over score[b] (redundant per q), ctx slice of 256 cols
// -> xvec[b][q*256..], q==0 writes attn_out, q==1 copies emb row.
// ---------------------------------------------------------------------------
__global__ __launch_bounds__(256) void attn_ctx_kernel(
    const float* __restrict__ score, const float* __restrict__ enc,
    const float* __restrict__ emb, const int* __restrict__ dec,
    float* __restrict__ attn_out, float* __restrict__ xvec) {
    const int b = blockIdx.x >> 2, q = blockIdx.x & 3;
    const int t = threadIdx.x;
    __shared__ float red[128];
    __shared__ float aw[128];
    float v = 0.0f;
    if (t < 128) {
        v = score[b * S_ + t];
        red[t] = v;
    }
    __syncthreads();
    for (int str = 64; str > 0; str >>= 1) {
        if (t < str) red[t] = fmaxf(red[t], red[t + str]);
        __syncthreads();
    }
    float m = red[0];
    __syncthreads();
    float e = 0.0f;
    if (t < 128) {
        e = expf(v - m);
        red[t] = e;
    }
    __syncthreads();
    for (int str = 64; str > 0; str >>= 1) {
        if (t < str) red[t] += red[t + str];
        __syncthreads();
    }
    float inv = 1.0f / red[0];
    if (t < 128) aw[t] = e * inv;
    __syncthreads();

    const int col = q * 256 + t;
    const float* ebase = enc + (size_t)b * S_ * H_ + col;
    float a0 = 0.0f, a1 = 0.0f, a2 = 0.0f, a3 = 0.0f;
    for (int s = 0; s < S_; s += 4) {
        a0 += aw[s + 0] * ebase[(size_t)(s + 0) * H_];
        a1 += aw[s + 1] * ebase[(size_t)(s + 1) * H_];
        a2 += aw[s + 2] * ebase[(size_t)(s + 2) * H_];
        a3 += aw[s + 3] * ebase[(size_t)(s + 3) * H_];
    }
    xvec[(size_t)b * (H_ + EMB_) + col] = (a0 + a1) + (a2 + a3);

    if (q == 0 && t < 128) attn_out[b * S_ + t] = aw[t];
    if (q == 1) {
        int tok = dec[b];
        float* xb = xvec + (size_t)b * (H_ + EMB_) + H_;
        xb[t] = emb[(size_t)tok * EMB_ + t];
        xb[t + 256] = emb[(size_t)tok * EMB_ + t + 256];
    }
}

// ---------------------------------------------------------------------------
// GRU gates (xm/hm already include their biases): state -> fp32 output region
// ---------------------------------------------------------------------------
__global__ void gates_kernel(const float* __restrict__ xm, const float* __restrict__ hm,
                             const float* __restrict__ hidden,
                             float* __restrict__ state_out) {
    const int idx = blockIdx.x * 256 + threadIdx.x;  // 0..65535
    const int b = idx >> 10, j = idx & (H_ - 1);
    const float* xmb = xm + (size_t)b * 3 * H_;
    const float* hmb = hm + (size_t)b * 3 * H_;
    float z = sigmoidf_(xmb[j] + hmb[j]);
    float r = sigmoidf_(xmb[H_ + j] + hmb[H_ + j]);
    float hc = tanhf(xmb[2 * H_ + j] + r * hmb[2 * H_ + j]);
    state_out[idx] = z * hidden[idx] + (1.0f - z) * hc;
}

// ---------------------------------------------------------------------------
extern "C" void kernel_launch(void* const* d_in, const int* in_sizes, int n_in,
                              void* d_out, int out_size, void* d_ws, size_t ws_size,
                              hipStream_t stream) {
    const int* dec_input = (const int*)d_in[0];
    const float* hidden = (const float*)d_in[1];
    const float* enc = (const float*)d_in[2];
    const float* emb = (const float*)d_in[3];
    const float* W1_k = (const float*)d_in[4];
    const float* W1_b = (const float*)d_in[5];
    const float* W2_k = (const float*)d_in[6];
    const float* W2_b = (const float*)d_in[7];
    const float* V_k = (const float*)d_in[8];
    const float* V_b = (const float*)d_in[9];
    const float* gru_k = (const float*)d_in[10];
    const float* gru_rk = (const float*)d_in[11];
    const float* gru_b = (const float*)d_in[12];
    const float* out_k = (const float*)d_in[13];
    const float* out_b = (const float*)d_in[14];

    float* out = (float*)d_out;
    float* probs_out = out;                              // 64*32000 = 2,048,000 f
    float* state_out = out + (size_t)B_ * VOCAB_;        // 64*1024
    float* attn_out = state_out + (size_t)B_ * H_;       // 64*128

    // Scratch lives in the (dead until step 7) probs output region:
    // hproj 65536 | hm 196608 | score 8192 | xvec 98304 | xm 196608
    // = 565,248 floats < 2,048,000. Every segment is fully written before
    // read each iteration; probs_mfma overwrites the whole region last and
    // reads only state_out/out_k/out_b. d_ws deliberately untouched.
    float* hproj = probs_out;
    float* hm = hproj + B_ * H_;
    float* score = hm + B_ * 3 * H_;
    float* xvec = score + B_ * S_;
    float* xm = xvec + B_ * (H_ + EMB_);

    // 1. pre-init accumulators with biases (fused, 1 launch)
    const int INIT_TOTAL = B_ * H_ + 2 * B_ * 3 * H_ + B_ * S_;  // 466944
    init_bias4_kernel<<<(INIT_TOTAL + 255) / 256, 256, 0, stream>>>(
        hproj, W2_b, hm, xm, gru_b, score, V_b);

    // 2. hproj += hidden @ W2_k AND hm += hidden @ gru_rk (fused dual launch)
    gemm_dual_kernel<<<dim3(64, 8), 256, 0, stream>>>(hidden, W2_k, gru_rk, hproj,
                                                      hm, H_ / 8);
    // 3. score += fused tanh/V epilogue of enc @ W1  (4 n-tiles x 128 m-tiles)
    score_mfma_kernel<<<dim3(4, 128), 256, 0, stream>>>(enc, W1_k, W1_b, V_k, hproj,
                                                        score);
    // 4. softmax + context + buildx (fused) -> attn_out, xvec
    attn_ctx_kernel<<<B_ * 4, 256, 0, stream>>>(score, enc, emb, dec_input, attn_out,
                                                xvec);
    // 5. xm += x @ gru_k          (48 x 8 -> 384 blocks, 6 k-steps)
    gemm_mfma_atomic_kernel<1><<<dim3(48, 8), 256, 0, stream>>>(xvec, H_ + EMB_, gru_k,
                                                                3 * H_, xm, (H_ + EMB_) / 8);
    // 6. gates -> state output region
    gates_kernel<<<(B_ * H_) / 256, 256, 0, stream>>>(xm, hm, hidden, state_out);
    // 7. probs = state @ out_k + out_b  (500 blocks, NF=1, direct store)
    probs_mfma_kernel<<<dim3(VOCAB_ / 64), 256, 0, stream>>>(state_out, out_k, out_b,
                                                             probs_out);
}